// Round 1
// baseline (2627.553 us; speedup 1.0000x reference)
//
#include <hip/hip_runtime.h>

#define BB 4
#define CH 64
#define HH 96
#define WW 96
#define DD 8
#define NS 243   // (2D+1)*(2S+1)^2 = 3*9*9
#define CC 4     // c-chunk staged in LDS

// ---------------------------------------------------------------------------
// Kernel 1: per-pixel masks. mask = clip(sum_d alpha, 0, 1), shape (B,H,W)
// ---------------------------------------------------------------------------
__global__ void masks_kernel(const float* __restrict__ a1,
                             const float* __restrict__ a2,
                             float* __restrict__ m1,
                             float* __restrict__ m2) {
    int p = blockIdx.x * 256 + threadIdx.x;
    if (p >= BB * HH * WW) return;
    float4 x0 = ((const float4*)a1)[p * 2];
    float4 x1 = ((const float4*)a1)[p * 2 + 1];
    float4 y0 = ((const float4*)a2)[p * 2];
    float4 y1 = ((const float4*)a2)[p * 2 + 1];
    float s1 = ((x0.x + x0.y) + (x0.z + x0.w)) + ((x1.x + x1.y) + (x1.z + x1.w));
    float s2 = ((y0.x + y0.y) + (y0.z + y0.w)) + ((y1.x + y1.y) + (y1.z + y1.w));
    m1[p] = fminf(fmaxf(s1, 0.0f), 1.0f);
    m2[p] = fminf(fmaxf(s2, 0.0f), 1.0f);
}

// ---------------------------------------------------------------------------
// Kernel 2: cost_volume_mask (B,NS,H,W,D), 287 MB. One block per (b,s);
// 256 threads x 72 float4 stores, fully coalesced full-line writes.
// m1/m2 are 147 KB -> L1/L2 resident.
// ---------------------------------------------------------------------------
__global__ __launch_bounds__(256)
void maskvol_kernel(const float* __restrict__ m1,
                    const float* __restrict__ m2,
                    float* __restrict__ out) {
    int bs = blockIdx.x;            // b*NS + s
    int b = bs / NS;
    int s = bs % NS;
    int k = s / 81;
    int i = (s / 9) % 9;
    int j = s % 9;
    const float* m1b = m1 + b * HH * WW;
    const float* m2b = m2 + b * HH * WW;
    float4* o4 = (float4*)out + (size_t)bs * (HH * WW * DD / 4);
    for (int n = threadIdx.x; n < HH * WW * DD / 4; n += 256) {
        int y = n / 192;            // 192 float4 per y-row
        int r = n - y * 192;
        int x = r >> 1;
        int zb = (r & 1) * 4;       // z of component q is zb+q
        float m1v = m1b[y * WW + x];
        int yy = y + i - 4;
        int xx = x + j - 4;
        float m2v = 1.0f;           // mask pad value
        if ((unsigned)yy < HH && (unsigned)xx < WW) m2v = m2b[yy * WW + xx];
        float pv = m1v * m2v;       // value when zz in range
        float4 v;
        float* vp = (float*)&v;
        #pragma unroll
        for (int q = 0; q < 4; ++q) {
            int zz = zb + q + k - 1;
            float r0 = ((unsigned)zz < DD) ? pv : m1v;  // z-pad mask = 1.0
            vp[q] = fminf(fmaxf(r0, 0.0f), 1.0f);
        }
        o4[n] = v;
    }
}

// ---------------------------------------------------------------------------
// Kernel 3: cost volume. Block = (i,y,b) via XCD-swizzled 1D grid (the 9
// i-siblings of each (b,y) stay on one XCD -> rows fetched once per XCD).
// 192 threads = 24 xb * 8 z; acc[k3][j9][x4] = 108 regs.
// __launch_bounds__(192, 4): forces total reg allocation <= 128 (the VGPR
// count the compiler already reported) so residency reaches ~5 blocks/CU
// instead of 2 -- the kernel was latency-bound at 16.7% occupancy.
// Main-loop ds_read_b128 patterns are in the inherent 8-touch/bank class
// (same as a linear b128 read) -> no padding needed. Epilogue transpose is
// XOR-swizzled on 16B blocks (bb ^= (bb>>3)&7, applied both sides) to kill
// its 8-way b32 write conflict, and batches 9 j-slices per barrier pair
// (6 barriers total instead of 54).
// ---------------------------------------------------------------------------
__global__ __launch_bounds__(192, 4)
void cost_kernel(const float* __restrict__ f1,
                 const float* __restrict__ f2,
                 float* __restrict__ out) {
    const int L = blockIdx.x;             // 0..3455
    const int u = L % 72;
    const int i = u >> 3;                 // 0..8
    const int g = (L / 72) * 8 + (u & 7); // 0..383 = b*HH + y
    const int b = g / HH;
    const int y = g % HH;
    const int tid = threadIdx.x;
    const int xb = tid >> 3;              // 0..23
    const int z  = tid & 7;               // 0..7
    const int yp = y + i - 4;

    // ---- fast path: whole source row is zero-pad -> cost == 0 ----
    if (yp < 0 || yp >= HH) {
        #pragma unroll
        for (int k = 0; k < 3; ++k)
            #pragma unroll
            for (int j = 0; j < 9; ++j) {
                int s = k * 81 + i * 9 + j;
                float4* o4 = (float4*)out + ((size_t)(b * NS + s) * HH + y) * 192;
                o4[tid] = make_float4(0.f, 0.f, 0.f, 0.f);
            }
        return;
    }

    // single shared pool: f1s = CC*8*96 = 3072 floats, f2s = CC*10*104 = 4160
    // floats (7232 total, 28928 B). Epilogue reuses the pool as 9x768 scratch.
    __shared__ __align__(16) float smem[CC * 8 * 96 + CC * 10 * 104];
    float (*f1s)[8][96]   = (float (*)[8][96])smem;
    float (*f2s)[10][104] = (float (*)[10][104])(smem + CC * 8 * 96);

    for (int n = tid; n < CC * 10 * 104; n += 192)
        ((float*)f2s)[n] = 0.0f;

    const int xs = tid >> 1;        // staging pixel 0..95
    const int zb = (tid & 1) * 4;   // staging z-base (float4 = z zb..zb+3)

    // row base pointers in float4 units; per-channel stride = HH*192
    const float4* f1r = (const float4*)f1 + ((size_t)(b * CH) * HH + y)  * 192;
    const float4* f2r = (const float4*)f2 + ((size_t)(b * CH) * HH + yp) * 192;

    float4 p1[CC], p2[CC];
    #pragma unroll
    for (int c = 0; c < CC; ++c) {
        p1[c] = f1r[(size_t)c * (HH * 192) + tid];
        p2[c] = f2r[(size_t)c * (HH * 192) + tid];
    }

    float acc[3][9][4];
    #pragma unroll
    for (int k = 0; k < 3; ++k)
        #pragma unroll
        for (int j = 0; j < 9; ++j)
            #pragma unroll
            for (int t = 0; t < 4; ++t)
                acc[k][j][t] = 0.0f;

    for (int c0 = 0; c0 < CH; c0 += CC) {
        __syncthreads();  // previous chunk's LDS reads complete
        #pragma unroll
        for (int c = 0; c < CC; ++c) {
            f1s[c][zb + 0][xs] = p1[c].x;
            f1s[c][zb + 1][xs] = p1[c].y;
            f1s[c][zb + 2][xs] = p1[c].z;
            f1s[c][zb + 3][xs] = p1[c].w;
            f2s[c][zb + 1][xs + 4] = p2[c].x;   // plane index = z+1
            f2s[c][zb + 2][xs + 4] = p2[c].y;
            f2s[c][zb + 3][xs + 4] = p2[c].z;
            f2s[c][zb + 4][xs + 4] = p2[c].w;
        }
        if (c0 + CC < CH) {   // prefetch next chunk; latency hidden by compute
            #pragma unroll
            for (int c = 0; c < CC; ++c) {
                p1[c] = f1r[(size_t)(c0 + CC + c) * (HH * 192) + tid];
                p2[c] = f2r[(size_t)(c0 + CC + c) * (HH * 192) + tid];
            }
        }
        __syncthreads();

        #pragma unroll
        for (int c = 0; c < CC; ++c) {
            float4 f1v = *(const float4*)&f1s[c][z][xb * 4];
            float f1a[4] = {f1v.x, f1v.y, f1v.z, f1v.w};
            #pragma unroll
            for (int k = 0; k < 3; ++k) {
                float4 w0 = *(const float4*)&f2s[c][z + k][xb * 4];
                float4 w1 = *(const float4*)&f2s[c][z + k][xb * 4 + 4];
                float4 w2 = *(const float4*)&f2s[c][z + k][xb * 4 + 8];
                float w[12] = {w0.x, w0.y, w0.z, w0.w,
                               w1.x, w1.y, w1.z, w1.w,
                               w2.x, w2.y, w2.z, w2.w};
                #pragma unroll
                for (int t = 0; t < 4; ++t)
                    #pragma unroll
                    for (int j = 0; j < 9; ++j)
                        acc[k][j][t] = fmaf(f1a[t], w[t + j], acc[k][j][t]);
            }
        }
    }

    // ---- epilogue: swizzled LDS transpose, 9 slices per barrier pair ----
    __syncthreads();                // all compute reads of smem done
    float* sbuf = smem;             // 9*768 = 6912 floats <= 7232
    int wsw[4];
    #pragma unroll
    for (int t = 0; t < 4; ++t) {
        int d  = (xb * 4 + t) * 8 + z;     // dword index 0..767 (x*8+z)
        int bb = d >> 2;                   // 16B block 0..191
        int sb = bb ^ ((bb >> 3) & 7);     // XOR swizzle (bijective, 0..191)
        wsw[t] = (sb << 2) | (d & 3);
    }
    const int rsw = (tid ^ ((tid >> 3) & 7)) << 2;

    #pragma unroll
    for (int k = 0; k < 3; ++k) {
        #pragma unroll
        for (int j = 0; j < 9; ++j)
            #pragma unroll
            for (int t = 0; t < 4; ++t)
                sbuf[j * 768 + wsw[t]] = acc[k][j][t] * 0.015625f;
        __syncthreads();
        #pragma unroll
        for (int j = 0; j < 9; ++j) {
            int s = k * 81 + i * 9 + j;
            float4 v = *(float4*)&sbuf[j * 768 + rsw];
            float4* o4 = (float4*)out + ((size_t)(b * NS + s) * HH + y) * 192;
            o4[tid] = v;
        }
        __syncthreads();            // before next k overwrites sbuf
    }
}

// ---------------------------------------------------------------------------
extern "C" void kernel_launch(void* const* d_in, const int* in_sizes, int n_in,
                              void* d_out, int out_size, void* d_ws, size_t ws_size,
                              hipStream_t stream) {
    const float* f1 = (const float*)d_in[0];  // mpi1_features (4,64,96,96,8)
    const float* a1 = (const float*)d_in[1];  // mpi1_alpha    (4,1,96,96,8)
    const float* f2 = (const float*)d_in[2];  // mpi2_features
    const float* a2 = (const float*)d_in[3];  // mpi2_alpha

    float* out      = (float*)d_out;
    float* out_cost = out;                                   // (B,NS,H,W,D)
    float* out_mask = out + (size_t)BB * NS * HH * WW * DD;  // second output

    float* m1 = (float*)d_ws;                 // B*H*W floats
    float* m2 = m1 + BB * HH * WW;            // B*H*W floats (295 KB total)

    masks_kernel<<<(BB * HH * WW + 255) / 256, 256, 0, stream>>>(a1, a2, m1, m2);
    maskvol_kernel<<<BB * NS, 256, 0, stream>>>(m1, m2, out_mask);
    cost_kernel<<<3456, 192, 0, stream>>>(f1, f2, out_cost);
}

// Round 3
// 845.792 us; speedup vs baseline: 3.1066x; 3.1066x over previous
//
#include <hip/hip_runtime.h>

#define BB 4
#define CH 64
#define HH 96
#define WW 96
#define DD 8
#define NS 243   // (2D+1)*(2S+1)^2 = 3*9*9
#define CC 2     // c-chunk staged in LDS

// ---------------------------------------------------------------------------
// Kernel 1: per-pixel masks. mask = clip(sum_d alpha, 0, 1), shape (B,H,W)
// ---------------------------------------------------------------------------
__global__ void masks_kernel(const float* __restrict__ a1,
                             const float* __restrict__ a2,
                             float* __restrict__ m1,
                             float* __restrict__ m2) {
    int p = blockIdx.x * 256 + threadIdx.x;
    if (p >= BB * HH * WW) return;
    float4 x0 = ((const float4*)a1)[p * 2];
    float4 x1 = ((const float4*)a1)[p * 2 + 1];
    float4 y0 = ((const float4*)a2)[p * 2];
    float4 y1 = ((const float4*)a2)[p * 2 + 1];
    float s1 = ((x0.x + x0.y) + (x0.z + x0.w)) + ((x1.x + x1.y) + (x1.z + x1.w));
    float s2 = ((y0.x + y0.y) + (y0.z + y0.w)) + ((y1.x + y1.y) + (y1.z + y1.w));
    m1[p] = fminf(fmaxf(s1, 0.0f), 1.0f);
    m2[p] = fminf(fmaxf(s2, 0.0f), 1.0f);
}

// ---------------------------------------------------------------------------
// Kernel 2: cost_volume_mask (B,NS,H,W,D), 287 MB. grid (BB*NS, 4): the y=4
// split quadruples wave count (3888 waves -> 15.5k) to cover store-drain
// and load latency; writes stay fully coalesced 1 KB/wave.
// ---------------------------------------------------------------------------
__global__ __launch_bounds__(256)
void maskvol_kernel(const float* __restrict__ m1,
                    const float* __restrict__ m2,
                    float* __restrict__ out) {
    int bs = blockIdx.x;            // b*NS + s
    int q  = blockIdx.y;            // 0..3 (y-range quarter)
    int b = bs / NS;
    int s = bs % NS;
    int k = s / 81;
    int i = (s / 9) % 9;
    int j = s % 9;
    const float* m1b = m1 + b * HH * WW;
    const float* m2b = m2 + b * HH * WW;
    float4* o4 = (float4*)out + (size_t)bs * (HH * WW * DD / 4);
    int n_end = (q + 1) * 4608;     // 18432/4 per quarter
    for (int n = q * 4608 + threadIdx.x; n < n_end; n += 256) {
        int y = n / 192;            // 192 float4 per y-row
        int r = n - y * 192;
        int x = r >> 1;
        int zb = (r & 1) * 4;       // z of component q is zb+q
        float m1v = m1b[y * WW + x];
        int yy = y + i - 4;
        int xx = x + j - 4;
        float m2v = 1.0f;           // mask pad value
        if ((unsigned)yy < HH && (unsigned)xx < WW) m2v = m2b[yy * WW + xx];
        float pv = m1v * m2v;       // value when zz in range
        float4 v;
        float* vp = (float*)&v;
        #pragma unroll
        for (int t = 0; t < 4; ++t) {
            int zz = zb + t + k - 1;
            float r0 = ((unsigned)zz < DD) ? pv : m1v;  // z-pad mask = 1.0
            vp[t] = fminf(fmaxf(r0, 0.0f), 1.0f);
        }
        o4[n] = v;
    }
}

// ---------------------------------------------------------------------------
// Kernel 3: cost volume, k-SPLIT. Block = (k,i,y,b); each block computes one
// z-offset k -> acc[9][4] = 36 regs instead of 108. Round-0/1 established
// VGPR pool ~= 1024/CU (128 regs -> 8 waves/CU = 2 blocks, latency-bound at
// all pipes <25% busy). __launch_bounds__(192,3) caps regs at 1024/12 = 85
// (natural pressure ~80 with CC=2) -> 4 blocks/CU resident.
// Prefetch is issued AFTER the second barrier: __syncthreads emits
// s_waitcnt vmcnt(0), so loads issued before it were drained every chunk
// (full HBM latency exposed); issued after, they overlap the compute phase.
// Epilogue: XOR-swizzled transpose (2-way banks = free), 3 j-slices per
// barrier pair.
// ---------------------------------------------------------------------------
__global__ __launch_bounds__(192, 3)
void cost_kernel(const float* __restrict__ f1,
                 const float* __restrict__ f2,
                 float* __restrict__ out) {
    const int L = blockIdx.x;             // 0..10367
    const int u = L % 216;
    const int t9 = u >> 3;                // 0..26
    const int i = t9 % 9;                 // 0..8
    const int k = t9 / 9;                 // 0..2
    const int g = (L / 216) * 8 + (u & 7);// 0..383 = b*HH + y
    const int b = g / HH;
    const int y = g % HH;
    const int tid = threadIdx.x;
    const int xb = tid >> 3;              // 0..23
    const int z  = tid & 7;               // 0..7
    const int yp = y + i - 4;

    // ---- fast path: whole source row is zero-pad -> cost == 0 ----
    if (yp < 0 || yp >= HH) {
        #pragma unroll
        for (int j = 0; j < 9; ++j) {
            int s = k * 81 + i * 9 + j;
            float4* o4 = (float4*)out + ((size_t)(b * NS + s) * HH + y) * 192;
            o4[tid] = make_float4(0.f, 0.f, 0.f, 0.f);
        }
        return;
    }

    // f1s = CC*8*96 = 1536 floats, f2s = CC*10*104 = 2080 floats.
    // 3616 floats = 14464 B -> LDS allows 11 blocks; regs (85) allow 4.
    __shared__ __align__(16) float smem[CC * 8 * 96 + CC * 10 * 104];
    float (*f1s)[8][96]   = (float (*)[8][96])smem;
    float (*f2s)[10][104] = (float (*)[10][104])(smem + CC * 8 * 96);

    for (int n = tid; n < CC * 10 * 104; n += 192)
        ((float*)f2s)[n] = 0.0f;        // halos (planes 0,9; x 0..3,100..103)

    const int xs = tid >> 1;        // staging pixel 0..95
    const int zb = (tid & 1) * 4;   // staging z-base (float4 = z zb..zb+3)

    const float4* f1r = (const float4*)f1 + ((size_t)(b * CH) * HH + y)  * 192;
    const float4* f2r = (const float4*)f2 + ((size_t)(b * CH) * HH + yp) * 192;

    float4 p1[CC], p2[CC];
    #pragma unroll
    for (int c = 0; c < CC; ++c) {
        p1[c] = f1r[(size_t)c * (HH * 192) + tid];
        p2[c] = f2r[(size_t)c * (HH * 192) + tid];
    }

    float acc[9][4];
    #pragma unroll
    for (int j = 0; j < 9; ++j)
        #pragma unroll
        for (int t = 0; t < 4; ++t)
            acc[j][t] = 0.0f;

    for (int c0 = 0; c0 < CH; c0 += CC) {
        __syncthreads();  // prev compute's LDS reads done; prefetch drained here
        #pragma unroll
        for (int c = 0; c < CC; ++c) {
            f1s[c][zb + 0][xs] = p1[c].x;
            f1s[c][zb + 1][xs] = p1[c].y;
            f1s[c][zb + 2][xs] = p1[c].z;
            f1s[c][zb + 3][xs] = p1[c].w;
            f2s[c][zb + 1][xs + 4] = p2[c].x;   // plane index = z+1
            f2s[c][zb + 2][xs + 4] = p2[c].y;
            f2s[c][zb + 3][xs + 4] = p2[c].z;
            f2s[c][zb + 4][xs + 4] = p2[c].w;
        }
        __syncthreads();
        // prefetch AFTER the barrier: latency hidden under this chunk's compute
        if (c0 + CC < CH) {
            #pragma unroll
            for (int c = 0; c < CC; ++c) {
                p1[c] = f1r[(size_t)(c0 + CC + c) * (HH * 192) + tid];
                p2[c] = f2r[(size_t)(c0 + CC + c) * (HH * 192) + tid];
            }
        }

        #pragma unroll
        for (int c = 0; c < CC; ++c) {
            float4 f1v = *(const float4*)&f1s[c][z][xb * 4];
            float f1a[4] = {f1v.x, f1v.y, f1v.z, f1v.w};
            float4 w0 = *(const float4*)&f2s[c][z + k][xb * 4];
            float4 w1 = *(const float4*)&f2s[c][z + k][xb * 4 + 4];
            float4 w2 = *(const float4*)&f2s[c][z + k][xb * 4 + 8];
            float w[12] = {w0.x, w0.y, w0.z, w0.w,
                           w1.x, w1.y, w1.z, w1.w,
                           w2.x, w2.y, w2.z, w2.w};
            #pragma unroll
            for (int t = 0; t < 4; ++t)
                #pragma unroll
                for (int j = 0; j < 9; ++j)
                    acc[j][t] = fmaf(f1a[t], w[t + j], acc[j][t]);
        }
    }

    // ---- epilogue: swizzled LDS transpose, 3 slices per barrier pair ----
    __syncthreads();                // all compute reads of smem done
    float* sbuf = smem;             // 3*768 = 2304 floats <= 3616
    int wsw[4];
    #pragma unroll
    for (int t = 0; t < 4; ++t) {
        int d  = (xb * 4 + t) * 8 + z;     // dword index 0..767 (x*8+z)
        int bb = d >> 2;                   // 16B block 0..191
        int sb = bb ^ ((bb >> 3) & 7);     // XOR swizzle (bijective)
        wsw[t] = (sb << 2) | (d & 3);
    }
    const int rsw = (tid ^ ((tid >> 3) & 7)) << 2;

    #pragma unroll
    for (int jb = 0; jb < 3; ++jb) {
        #pragma unroll
        for (int jj = 0; jj < 3; ++jj)
            #pragma unroll
            for (int t = 0; t < 4; ++t)
                sbuf[jj * 768 + wsw[t]] = acc[jb * 3 + jj][t] * 0.015625f;
        __syncthreads();
        #pragma unroll
        for (int jj = 0; jj < 3; ++jj) {
            int s = k * 81 + i * 9 + jb * 3 + jj;
            float4 v = *(float4*)&sbuf[jj * 768 + rsw];
            float4* o4 = (float4*)out + ((size_t)(b * NS + s) * HH + y) * 192;
            o4[tid] = v;
        }
        __syncthreads();            // before next batch overwrites sbuf
    }
}

// ---------------------------------------------------------------------------
extern "C" void kernel_launch(void* const* d_in, const int* in_sizes, int n_in,
                              void* d_out, int out_size, void* d_ws, size_t ws_size,
                              hipStream_t stream) {
    const float* f1 = (const float*)d_in[0];  // mpi1_features (4,64,96,96,8)
    const float* a1 = (const float*)d_in[1];  // mpi1_alpha    (4,1,96,96,8)
    const float* f2 = (const float*)d_in[2];  // mpi2_features
    const float* a2 = (const float*)d_in[3];  // mpi2_alpha

    float* out      = (float*)d_out;
    float* out_cost = out;                                   // (B,NS,H,W,D)
    float* out_mask = out + (size_t)BB * NS * HH * WW * DD;  // second output

    float* m1 = (float*)d_ws;                 // B*H*W floats
    float* m2 = m1 + BB * HH * WW;            // B*H*W floats (295 KB total)

    masks_kernel<<<(BB * HH * WW + 255) / 256, 256, 0, stream>>>(a1, a2, m1, m2);
    maskvol_kernel<<<dim3(BB * NS, 4), 256, 0, stream>>>(m1, m2, out_mask);
    cost_kernel<<<10368, 192, 0, stream>>>(f1, f2, out_cost);
}